// Round 5
// baseline (41.798 us; speedup 1.0000x reference)
//
#include <hip/hip_runtime.h>
#include <math.h>

#define EPS 1e-5f

// Single-launch producer/consumer. Grid = 256 blocks (1 per CU -> all
// co-resident, spin-wait is safe). Blocks 0..63 additionally build one row of
// the 64-token table (the whole net up to `hs` depends only on token id).
// ws float layout: [0,4096) HS table; [4096,4160) scores; int flag at 4160.
__global__ __launch_bounds__(256, 1) void slot_one(
    const int* __restrict__ seq,
    const float* __restrict__ embed,
    const float* __restrict__ W1, const float* __restrict__ b1,
    const float* __restrict__ W2, const float* __restrict__ b2,
    const float* __restrict__ gamma, const float* __restrict__ beta,
    const float* __restrict__ Wq, const float* __restrict__ bq,
    const float* __restrict__ Wo, const float* __restrict__ bo,
    float* __restrict__ wsf, int* __restrict__ flag,
    float* __restrict__ out)
{
    __shared__ float HS[64][65];   // pad 65: row+col patterns conflict-free
    __shared__ int   hist[4][64];
    __shared__ float e[64];
    __shared__ float Up[2][128];
    __shared__ float Ux[128];
    __shared__ float Hp[4][64];
    __shared__ float qv[64];
    __shared__ int   tlast_s;

    const int tid = threadIdx.x;
    const int wv  = tid >> 6;
    const int ln  = tid & 63;
    const int b   = blockIdx.x;
    const int* row = seq + b * 4096;

    hist[wv][ln] = 0;

    // Issue own-row seq loads immediately (latency hides under everything).
    int4 s0 = reinterpret_cast<const int4*>(row)[tid];
    int4 s1 = reinterpret_cast<const int4*>(row)[tid + 256];
    int4 s2 = reinterpret_cast<const int4*>(row)[tid + 512];
    int4 s3 = reinterpret_cast<const int4*>(row)[tid + 768];

    // Register prefetch: wave0 = Wo column + bo; wave1 = Wq column + bq.
    float wcol[64];
    float bias = 0.f;
    if (wv == 0) {
        #pragma unroll
        for (int k = 0; k < 64; ++k) wcol[k] = Wo[k * 64 + ln];
        bias = bo[ln];
    } else if (wv == 1) {
        #pragma unroll
        for (int k = 0; k < 64; ++k) wcol[k] = Wq[k * 64 + ln];
        bias = bq[ln];
    }

    if (b < 64 && tid < 64) e[tid] = embed[b * 64 + tid];
    __syncthreads();   // hist zeroed, e ready

    // ---------------- producers: build table row b ----------------
    if (b < 64) {
        {   // U = relu(e@W1+b1): thread (j=tid&127, half h), W1 direct from L2
            int j = tid & 127, h = tid >> 7, k0 = h << 5;
            float acc = 0.f;
            #pragma unroll
            for (int k = 0; k < 32; ++k)
                acc = fmaf(e[k0 + k], W1[(k0 + k) * 128 + j], acc);
            Up[h][j] = acc;
        }
        __syncthreads();
        if (tid < 128) Ux[tid] = fmaxf(b1[tid] + Up[0][tid] + Up[1][tid], 0.f);
        __syncthreads();
        {   // H = e + U@W2 + b2: thread (j=tid&63, quarter qd)
            int j = tid & 63, qd = tid >> 6, k0 = qd << 5;
            float acc = 0.f;
            #pragma unroll
            for (int k = 0; k < 32; ++k)
                acc = fmaf(Ux[k0 + k], W2[(k0 + k) * 64 + j], acc);
            Hp[qd][j] = acc;
        }
        __syncthreads();
        if (tid < 64) {   // LN + gamma/beta + gate norm
            float h = e[tid] + b2[tid] + Hp[0][tid] + Hp[1][tid] + Hp[2][tid] + Hp[3][tid];
            float s = h;
            #pragma unroll
            for (int off = 1; off < 64; off <<= 1) s += __shfl_xor(s, off);
            float mu = s * (1.f / 64.f);
            float d = h - mu;
            float v = d * d;
            #pragma unroll
            for (int off = 1; off < 64; off <<= 1) v += __shfl_xor(v, off);
            float rstd = rsqrtf(v * (1.f / 64.f) + EPS);
            float hs = d * rstd * gamma[tid] + beta[tid];
            wsf[b * 64 + tid] = hs;
            float ss = hs * hs;
            #pragma unroll
            for (int off = 1; off < 64; off <<= 1) ss += __shfl_xor(ss, off);
            if (tid == 0) wsf[4096 + b] = sqrtf(ss);
        }
        __syncthreads();          // all table stores issued (vmcnt drained)
        __threadfence();          // agent release: write back L2
        if (tid == 0) atomicAdd(flag, 1);
    }

    // ---------------- all blocks: LDS histogram of own row ----------------
    atomicAdd(&hist[wv][s0.x], 1); atomicAdd(&hist[wv][s0.y], 1);
    atomicAdd(&hist[wv][s0.z], 1); atomicAdd(&hist[wv][s0.w], 1);
    atomicAdd(&hist[wv][s1.x], 1); atomicAdd(&hist[wv][s1.y], 1);
    atomicAdd(&hist[wv][s1.z], 1); atomicAdd(&hist[wv][s1.w], 1);
    atomicAdd(&hist[wv][s2.x], 1); atomicAdd(&hist[wv][s2.y], 1);
    atomicAdd(&hist[wv][s2.z], 1); atomicAdd(&hist[wv][s2.w], 1);
    atomicAdd(&hist[wv][s3.x], 1);                  // pos 4092 included
    if (tid != 255) {
        atomicAdd(&hist[wv][s3.y], 1);
        atomicAdd(&hist[wv][s3.z], 1);
        atomicAdd(&hist[wv][s3.w], 1);
    } else {
        tlast_s = s3.w;                             // pos 4095
    }
    __syncthreads();   // hist + tlast complete

    // ---------------- wait for table, then acquire ----------------
    if (tid == 0) {
        while (atomicAdd(flag, 0) < 64) __builtin_amdgcn_s_sleep(2);
    }
    __syncthreads();
    __threadfence();   // agent acquire: invalidate local L2 before table reads

    // Stage HS table (16KB) + score.
    #pragma unroll
    for (int i = 0; i < 4; ++i) {
        int idx4 = tid + 256 * i;
        float4 v = reinterpret_cast<const float4*>(wsf)[idx4];
        int t = idx4 >> 4, j0 = (idx4 & 15) << 2;
        HS[t][j0] = v.x; HS[t][j0+1] = v.y; HS[t][j0+2] = v.z; HS[t][j0+3] = v.w;
    }
    float sc_r = (wv == 0) ? wsf[4096 + ln] : 0.f;
    __syncthreads();

    // Phase 1: wave0 -> slot counts; wave1 -> q = HS[tlast]@Wq + bq.
    int cnt_i = 0;
    if (wv == 0) {
        int h = hist[0][ln] + hist[1][ln] + hist[2][ln] + hist[3][ln];
        float my = sc_r;
        int S = 0;   // occurrences of tokens ranked strictly before ln
        for (int t2 = 0; t2 < 64; ++t2) {
            float s2 = __shfl(sc_r, t2);
            int   h2 = __shfl(h, t2);
            bool before = (s2 > my) || (s2 == my && t2 < ln);
            if (before) S += h2;
        }
        int rem = 64 - S;
        rem = rem < 0 ? 0 : rem;
        cnt_i = h < rem ? h : rem;
    } else if (wv == 1) {
        int tl = tlast_s;
        float acc = bias;
        #pragma unroll
        for (int k = 0; k < 64; ++k)
            acc = fmaf(HS[tl][k], wcol[k], acc);    // HS broadcast, wcol regs
        qv[ln] = acc;
    }
    __syncthreads();

    // Phase 2: wave0: logits -> softmax(w/ multiplicity) -> ctx -> out.
    if (wv == 0) {
        float acc = 0.f;
        #pragma unroll 8
        for (int k = 0; k < 64; ++k)
            acc = fmaf(qv[k], HS[ln][k], acc);
        float logit = acc * 0.125f;                 // / sqrt(64)
        float lm = (cnt_i > 0) ? logit : -1e30f;
        #pragma unroll
        for (int off = 1; off < 64; off <<= 1) lm = fmaxf(lm, __shfl_xor(lm, off));
        float wvv = (cnt_i > 0) ? (float)cnt_i * __expf(logit - lm) : 0.f;
        float z = wvv;
        #pragma unroll
        for (int off = 1; off < 64; off <<= 1) z += __shfl_xor(z, off);
        float w_reg = wvv / z;                      // lane t holds weight_t

        float cacc = 0.f;                           // ctx[ln]
        #pragma unroll 8
        for (int t2 = 0; t2 < 64; ++t2)
            cacc = fmaf(__shfl(w_reg, t2), HS[t2][ln], cacc);

        float oacc = bias;                          // out[ln]
        #pragma unroll
        for (int k = 0; k < 64; ++k)
            oacc = fmaf(__shfl(cacc, k), wcol[k], oacc);
        out[b * 64 + ln] = oacc;
    }
}

extern "C" void kernel_launch(void* const* d_in, const int* in_sizes, int n_in,
                              void* d_out, int out_size, void* d_ws, size_t ws_size,
                              hipStream_t stream) {
    const int*   seq   = (const int*)d_in[0];
    const float* embed = (const float*)d_in[1];
    const float* W1    = (const float*)d_in[2];
    const float* b1    = (const float*)d_in[3];
    const float* W2    = (const float*)d_in[4];
    const float* b2    = (const float*)d_in[5];
    const float* gamma = (const float*)d_in[6];
    const float* beta  = (const float*)d_in[7];
    const float* Wq    = (const float*)d_in[8];
    const float* bq    = (const float*)d_in[9];
    const float* Wo    = (const float*)d_in[10];
    const float* bo    = (const float*)d_in[11];
    float* out = (float*)d_out;
    float* wsf = (float*)d_ws;
    int*   flag = (int*)(wsf + 4160);
    (void)in_sizes; (void)n_in; (void)out_size; (void)ws_size;

    // Reset the producer/consumer flag each call (ws is poisoned / left dirty).
    hipMemsetAsync(flag, 0, sizeof(int), stream);
    slot_one<<<256, 256, 0, stream>>>(seq, embed, W1, b1, W2, b2, gamma, beta,
                                      Wq, bq, Wo, bo, wsf, flag, out);
}